// Round 1
// baseline (7580.325 us; speedup 1.0000x reference)
//
#include <hip/hip_runtime.h>
#include <hip/hip_bf16.h>

#define BATCH 128
#define SEQ   2048
#define INDIM 256
#define HDIM  256
#define G3    768   // 3*HDIM

typedef __attribute__((ext_vector_type(8))) short bfrag;          // 8 x bf16 (4 VGPRs)
typedef __attribute__((ext_vector_type(4))) float f32x4;          // MFMA accumulator
typedef __attribute__((ext_vector_type(8))) unsigned short us8;   // 16B of bf16

__device__ __forceinline__ unsigned short f2bf(float f) {
  __hip_bfloat16 h = __float2bfloat16(f);
  union { __hip_bfloat16 b; unsigned short u; } cvt;
  cvt.b = h;
  return cvt.u;
}
__device__ __forceinline__ float bf2f(unsigned short u) {
  union { unsigned int i; float f; } cvt;
  cvt.i = ((unsigned int)u) << 16;
  return cvt.f;
}

// ---------------------------------------------------------------------------
// Phase 1: gx[t][b][n] = x[b][t][:] . Wx[n][:] + bx[n], stored bf16, [SEQ][BATCH][768]
// One block per t. 512 threads = 8 waves; wave w owns output rows 16w..16w+15.
// ---------------------------------------------------------------------------
__global__ __launch_bounds__(512) void gx_gemm(const float* __restrict__ x,
                                               const float* __restrict__ Wx,
                                               const float* __restrict__ bx,
                                               unsigned short* __restrict__ gx) {
  const int t    = blockIdx.x;
  const int tid  = threadIdx.x;
  const int lane = tid & 63;
  const int w    = tid >> 6;   // 0..7

  // +8 pad (264) keeps 16B alignment (528B rows) and breaks the 512B-stride bank pattern
  __shared__ __attribute__((aligned(16))) unsigned short As[128][264];
  __shared__ __attribute__((aligned(16))) unsigned short Bs[64][264];

  // Stage A tile: As[b][k] = bf16(x[b][t][k]); each wave does 16 rows, 64 lanes x float4.
  for (int r = 0; r < 16; ++r) {
    const int b = w * 16 + r;
    const float4 v = *(const float4*)(x + ((size_t)b * SEQ + t) * INDIM + lane * 4);
    ushort4 u;
    u.x = f2bf(v.x); u.y = f2bf(v.y); u.z = f2bf(v.z); u.w = f2bf(v.w);
    *(ushort4*)&As[b][lane * 4] = u;
  }

  const int arow = w * 16 + (lane & 15);
  const int koff = (lane >> 4) * 8;

  for (int nc = 0; nc < 12; ++nc) {   // 12 N-chunks of 64 cols
    __syncthreads();                  // Bs free to overwrite
    for (int r = 0; r < 8; ++r) {
      const int j = w * 8 + r;
      const float4 v = *(const float4*)(Wx + ((size_t)(nc * 64 + j)) * INDIM + lane * 4);
      ushort4 u;
      u.x = f2bf(v.x); u.y = f2bf(v.y); u.z = f2bf(v.z); u.w = f2bf(v.w);
      *(ushort4*)&Bs[j][lane * 4] = u;
    }
    __syncthreads();

    f32x4 acc[4] = {{0.f,0.f,0.f,0.f},{0.f,0.f,0.f,0.f},{0.f,0.f,0.f,0.f},{0.f,0.f,0.f,0.f}};
#pragma unroll
    for (int kt = 0; kt < 8; ++kt) {
      const bfrag a = *(const bfrag*)&As[arow][kt * 32 + koff];
#pragma unroll
      for (int ni = 0; ni < 4; ++ni) {
        const bfrag b = *(const bfrag*)&Bs[ni * 16 + (lane & 15)][kt * 32 + koff];
        acc[ni] = __builtin_amdgcn_mfma_f32_16x16x32_bf16(a, b, acc[ni], 0, 0, 0);
      }
    }
    // Epilogue: C layout col=lane&15, row=(lane>>4)*4+i  (m89-verified)
#pragma unroll
    for (int ni = 0; ni < 4; ++ni) {
#pragma unroll
      for (int i = 0; i < 4; ++i) {
        const int row = w * 16 + (lane >> 4) * 4 + i;
        const int col = nc * 64 + ni * 16 + (lane & 15);
        gx[((size_t)t * BATCH + row) * G3 + col] = f2bf(acc[ni][i] + bx[col]);
      }
    }
  }
}

// ---------------------------------------------------------------------------
// Phase 2: sequential GRU scan.
// 32 blocks = 8 batch slices (16 rows) x 4 column chunks (64 h-cols).
// Block (s,q) holds Wh rows {g*256 + q*64 + j : g in {0,1,2}, j in [0,64)} in LDS (bf16),
// fully computes h_new for its 64 columns each step, exchanges h via global memory
// with double buffering + per-block monotonic publish counters (agent-scope atomics).
// ---------------------------------------------------------------------------
__global__ __launch_bounds__(256) void gru_scan(const unsigned short* __restrict__ gx,
                                                const float* __restrict__ Wh,
                                                const float* __restrict__ bh,
                                                float* __restrict__ hf,
                                                unsigned short* __restrict__ hb0,
                                                unsigned short* __restrict__ hb1,
                                                int* __restrict__ pub) {
  const int bid  = blockIdx.x;
  const int s    = bid >> 2;   // batch slice 0..7
  const int q    = bid & 3;    // column chunk 0..3
  const int tid  = threadIdx.x;
  const int lane = tid & 63;
  const int w    = tid >> 6;   // 0..3

  __shared__ __attribute__((aligned(16))) unsigned short Whs[192][264]; // ~101 KB
  __shared__ __attribute__((aligned(16))) unsigned short hs[16][264];   // ~8.4 KB
  __shared__ __attribute__((aligned(16))) float ghs[16][196];           // ~12.5 KB
  __shared__ float bhs[192];

  // Prologue: load this block's Wh chunk (f32 -> bf16) and bh chunk into LDS.
  for (int r = 0; r < 48; ++r) {
    const int m = w * 48 + r;                          // chunk row 0..191
    const int g = (m >> 6) * 256 + q * 64 + (m & 63);  // global Wh row
    const float4 v = *(const float4*)(Wh + (size_t)g * HDIM + lane * 4);
    ushort4 u;
    u.x = f2bf(v.x); u.y = f2bf(v.y); u.z = f2bf(v.z); u.w = f2bf(v.w);
    *(ushort4*)&Whs[m][lane * 4] = u;
  }
  if (tid < 192) {
    const int g = (tid >> 6) * 256 + q * 64 + (tid & 63);
    bhs[tid] = bh[g];
  }
  __syncthreads();

  const int hrow  = tid >> 4;          // 0..15
  const int hcol  = (tid & 15) * 16;   // 0..240 step 16
  const int gj    = tid & 63;          // column within chunk
  const int grow0 = tid >> 6;          // 0..3
  const int abase = lane & 15;
  const int koff  = (lane >> 4) * 8;

  for (int t = 0; t < SEQ; ++t) {
    const unsigned short* __restrict__ hsrc = (t & 1) ? hb1 : hb0;
    unsigned short* __restrict__ hdst       = (t & 1) ? hb0 : hb1;

    // Prefetch gx for this step early (independent of h) to hide HBM latency.
    unsigned short pxr[4], pxz[4], pxn[4];
#pragma unroll
    for (int rr = 0; rr < 4; ++rr) {
      const int row = rr * 4 + grow0;
      const size_t gb = ((size_t)t * BATCH + (s * 16 + row)) * G3 + q * 64 + gj;
      pxr[rr] = gx[gb];
      pxz[rr] = gx[gb + 256];
      pxn[rr] = gx[gb + 512];
    }

    // Stage h_t (bf16) rows s*16..s*16+15 into LDS.
    {
      const size_t base = ((size_t)(s * 16 + hrow)) * HDIM + hcol;
      const us8 v0 = *(const us8*)(hsrc + base);
      const us8 v1 = *(const us8*)(hsrc + base + 8);
      *(us8*)&hs[hrow][hcol]     = v0;
      *(us8*)&hs[hrow][hcol + 8] = v1;
    }
    __syncthreads();

    // gh = h . Wh_chunk^T : wave w computes chunk cols 48w..48w+47 (3 N-tiles x 8 K-tiles)
    bfrag a[8];
#pragma unroll
    for (int kt = 0; kt < 8; ++kt)
      a[kt] = *(const bfrag*)&hs[abase][kt * 32 + koff];

    f32x4 acc[3] = {{0.f,0.f,0.f,0.f},{0.f,0.f,0.f,0.f},{0.f,0.f,0.f,0.f}};
#pragma unroll
    for (int kt = 0; kt < 8; ++kt) {
#pragma unroll
      for (int ni = 0; ni < 3; ++ni) {
        const bfrag b = *(const bfrag*)&Whs[w * 48 + ni * 16 + abase][kt * 32 + koff];
        acc[ni] = __builtin_amdgcn_mfma_f32_16x16x32_bf16(a[kt], b, acc[ni], 0, 0, 0);
      }
    }
#pragma unroll
    for (int ni = 0; ni < 3; ++ni)
#pragma unroll
      for (int i = 0; i < 4; ++i)
        ghs[(lane >> 4) * 4 + i][w * 48 + ni * 16 + abase] = acc[ni][i];
    __syncthreads();

    // Gates: thread handles (j=gj, rows rr*4+grow0). All in f32; h state stays f32.
#pragma unroll
    for (int rr = 0; rr < 4; ++rr) {
      const int row = rr * 4 + grow0;
      const int b   = s * 16 + row;
      const int col = q * 64 + gj;
      const float xr = bf2f(pxr[rr]);
      const float xz = bf2f(pxz[rr]);
      const float xn = bf2f(pxn[rr]);
      const float hr = ghs[row][gj]       + bhs[gj];
      const float hz = ghs[row][64 + gj]  + bhs[64 + gj];
      const float hn = ghs[row][128 + gj] + bhs[128 + gj];
      const float rg = 1.f / (1.f + __expf(-(xr + hr)));
      const float zg = 1.f / (1.f + __expf(-(xz + hz)));
      const float ng = tanhf(xn + rg * hn);
      const size_t hidx = (size_t)b * HDIM + col;
      const float hold = hf[hidx];
      const float hnew = ng + zg * (hold - ng);
      hf[hidx]   = hnew;             // f32 state (own slice only -> race-free)
      hdst[hidx] = f2bf(hnew);       // bf16 copy for next step's MFMA A-operand
    }
    __syncthreads();  // drains the global stores (vmcnt 0) before publish

    // Publish h_{t+1} (release), then wait for the 3 peers of this slice (acquire).
    if (tid == 0)
      __hip_atomic_store(&pub[bid * 16], t + 1, __ATOMIC_RELEASE, __HIP_MEMORY_SCOPE_AGENT);
    if (tid < 4 && tid != q) {
      const int peer = ((s << 2) | tid) * 16;
      while (__hip_atomic_load(&pub[peer], __ATOMIC_ACQUIRE, __HIP_MEMORY_SCOPE_AGENT) < t + 1)
        __builtin_amdgcn_s_sleep(2);
    }
    __syncthreads();
  }
}

// ---------------------------------------------------------------------------
// Phase 3: out[b][o] = h_T[b][:] . Wfc[o][:] + bfc[o]   (tiny, f32)
// ---------------------------------------------------------------------------
__global__ __launch_bounds__(256) void gru_fc(const float* __restrict__ hf,
                                              const float* __restrict__ Wfc,
                                              const float* __restrict__ bfc,
                                              float* __restrict__ out) {
  const int tid = threadIdx.x;
  const int b = tid >> 1;
  const int o = tid & 1;
  float sum = bfc[o];
  for (int k = 0; k < HDIM; ++k)
    sum += hf[b * HDIM + k] * Wfc[o * HDIM + k];
  out[b * 2 + o] = sum;
}

// ---------------------------------------------------------------------------
extern "C" void kernel_launch(void* const* d_in, const int* in_sizes, int n_in,
                              void* d_out, int out_size, void* d_ws, size_t ws_size,
                              hipStream_t stream) {
  (void)in_sizes; (void)n_in; (void)out_size; (void)ws_size;
  const float* x   = (const float*)d_in[0];
  const float* Wx  = (const float*)d_in[1];
  const float* bx  = (const float*)d_in[2];
  const float* Wh  = (const float*)d_in[3];
  const float* bh  = (const float*)d_in[4];
  const float* Wfc = (const float*)d_in[5];
  const float* bfc = (const float*)d_in[6];
  float* out = (float*)d_out;

  char* ws = (char*)d_ws;
  const size_t GXB = (size_t)SEQ * BATCH * G3 * sizeof(unsigned short); // 402,653,184 B
  unsigned short* gx  = (unsigned short*)ws;
  float*          hf  = (float*)(ws + GXB);                          // 128*256*4 = 131072
  unsigned short* hb0 = (unsigned short*)(ws + GXB + (size_t)BATCH * HDIM * 4);
  unsigned short* hb1 = (unsigned short*)(ws + GXB + (size_t)BATCH * HDIM * 6);
  int*            pub = (int*)(ws + GXB + (size_t)BATCH * HDIM * 8); // 32 blocks x 64B

  // Zero h state (h0 = 0), both bf16 h buffers, and the publish counters.
  hipMemsetAsync(ws + GXB, 0, (size_t)BATCH * HDIM * 8 + 32 * 16 * sizeof(int), stream);

  gx_gemm<<<SEQ, 512, 0, stream>>>(x, Wx, bx, gx);
  gru_scan<<<32, 256, 0, stream>>>(gx, Wh, bh, hf, hb0, hb1, pub);
  gru_fc<<<1, 256, 0, stream>>>(hf, Wfc, bfc, out);
}

// Round 3
// 5420.956 us; speedup vs baseline: 1.3983x; 1.3983x over previous
//
#include <hip/hip_runtime.h>
#include <hip/hip_bf16.h>

#define BATCH 128
#define SEQ   2048
#define INDIM 256
#define HDIM  256
#define G3    768   // 3*HDIM

typedef __attribute__((ext_vector_type(8))) short bfrag;          // 8 x bf16 (4 VGPRs)
typedef __attribute__((ext_vector_type(4))) float f32x4;          // MFMA accumulator

__device__ __forceinline__ unsigned short f2bf(float f) {
  __hip_bfloat16 h = __float2bfloat16(f);
  union { __hip_bfloat16 b; unsigned short u; } cvt;
  cvt.b = h;
  return cvt.u;
}
__device__ __forceinline__ float bf2f(unsigned short u) {
  union { unsigned int i; float f; } cvt;
  cvt.i = ((unsigned int)u) << 16;
  return cvt.f;
}
__device__ __forceinline__ float fast_sigmoid(float x) {
  // 1/(1+e^-x); saturates correctly at +-inf
  return __builtin_amdgcn_rcpf(1.f + __expf(-x));
}
__device__ __forceinline__ float fast_tanh(float x) {
  // 1 - 2/(1+e^{2x}); saturates correctly at +-inf
  return 1.f - 2.f * __builtin_amdgcn_rcpf(1.f + __expf(2.f * x));
}

// ---------------------------------------------------------------------------
// Phase 1: gx[t][b][n] = x[b][t][:] . Wx[n][:] + bx[n], stored bf16, [SEQ][BATCH][768]
// One block per t. 512 threads = 8 waves; wave w owns output rows 16w..16w+15.
// ---------------------------------------------------------------------------
__global__ __launch_bounds__(512) void gx_gemm(const float* __restrict__ x,
                                               const float* __restrict__ Wx,
                                               const float* __restrict__ bx,
                                               unsigned short* __restrict__ gx) {
  const int t    = blockIdx.x;
  const int tid  = threadIdx.x;
  const int lane = tid & 63;
  const int w    = tid >> 6;   // 0..7

  __shared__ __attribute__((aligned(16))) unsigned short As[128][264];
  __shared__ __attribute__((aligned(16))) unsigned short Bs[64][264];

  for (int r = 0; r < 16; ++r) {
    const int b = w * 16 + r;
    const float4 v = *(const float4*)(x + ((size_t)b * SEQ + t) * INDIM + lane * 4);
    ushort4 u;
    u.x = f2bf(v.x); u.y = f2bf(v.y); u.z = f2bf(v.z); u.w = f2bf(v.w);
    *(ushort4*)&As[b][lane * 4] = u;
  }

  const int arow = w * 16 + (lane & 15);
  const int koff = (lane >> 4) * 8;

  for (int nc = 0; nc < 12; ++nc) {   // 12 N-chunks of 64 cols
    __syncthreads();
    for (int r = 0; r < 8; ++r) {
      const int j = w * 8 + r;
      const float4 v = *(const float4*)(Wx + ((size_t)(nc * 64 + j)) * INDIM + lane * 4);
      ushort4 u;
      u.x = f2bf(v.x); u.y = f2bf(v.y); u.z = f2bf(v.z); u.w = f2bf(v.w);
      *(ushort4*)&Bs[j][lane * 4] = u;
    }
    __syncthreads();

    f32x4 acc[4] = {{0.f,0.f,0.f,0.f},{0.f,0.f,0.f,0.f},{0.f,0.f,0.f,0.f},{0.f,0.f,0.f,0.f}};
#pragma unroll
    for (int kt = 0; kt < 8; ++kt) {
      const bfrag a = *(const bfrag*)&As[arow][kt * 32 + koff];
#pragma unroll
      for (int ni = 0; ni < 4; ++ni) {
        const bfrag b = *(const bfrag*)&Bs[ni * 16 + (lane & 15)][kt * 32 + koff];
        acc[ni] = __builtin_amdgcn_mfma_f32_16x16x32_bf16(a, b, acc[ni], 0, 0, 0);
      }
    }
#pragma unroll
    for (int ni = 0; ni < 4; ++ni) {
#pragma unroll
      for (int i = 0; i < 4; ++i) {
        const int row = w * 16 + (lane >> 4) * 4 + i;
        const int col = nc * 64 + ni * 16 + (lane & 15);
        gx[((size_t)t * BATCH + row) * G3 + col] = f2bf(acc[ni][i] + bx[col]);
      }
    }
  }
}

// ---------------------------------------------------------------------------
// Phase 2: sequential GRU scan, NO cross-block communication.
// 8 blocks (one per 16-row batch slice), 512 threads = 8 waves.
// Wave w owns gh columns 96w..96w+95 (6 tiles of 16): 5 tiles' B-fragments live
// in VGPRs (160 VGPR), the 6th in LDS. h state lives in f32 registers; bf16
// copy staged in LDS for the MFMA A-operand. 2 barriers per step.
// ---------------------------------------------------------------------------
__global__ __launch_bounds__(512, 2) void gru_scan(const unsigned short* __restrict__ gx,
                                                   const float* __restrict__ Wh,
                                                   const float* __restrict__ bh,
                                                   float* __restrict__ hf) {
  const int s    = blockIdx.x;   // batch slice 0..7
  const int tid  = threadIdx.x;
  const int lane = tid & 63;
  const int w    = tid >> 6;     // 0..7

  __shared__ __attribute__((aligned(16))) unsigned short hs[16][264];       //  8,448 B
  __shared__ __attribute__((aligned(16))) unsigned short WhL[8][16][264];   // 67,584 B
  __shared__ __attribute__((aligned(16))) float ghs[16][776];               // 49,664 B
  __shared__ float bhs[768];                                                //  3,072 B

  const int abase = lane & 15;
  const int koff  = (lane >> 4) * 8;

  // ---- Prologue ----
  // Zero h staging (h0 = 0).
  for (int i = tid; i < 16 * 264; i += 512) (&hs[0][0])[i] = 0;
  for (int i = tid; i < 768; i += 512) bhs[i] = bh[i];

  // Wave w stages its 6th column-tile (gh cols 96w+80..96w+95) into LDS.
  for (int rr = 0; rr < 16; ++rr) {
    const int grow = w * 96 + 80 + rr;
    const float4 v = *(const float4*)(Wh + (size_t)grow * HDIM + lane * 4);
    ushort4 u;
    u.x = f2bf(v.x); u.y = f2bf(v.y); u.z = f2bf(v.z); u.w = f2bf(v.w);
    *(ushort4*)&WhL[w][rr][lane * 4] = u;
  }

  // 5 column-tiles of B-fragments in registers (all indices compile-time).
  bfrag wr[5][8];
#pragma unroll
  for (int ct = 0; ct < 5; ++ct) {
    const int grow = w * 96 + ct * 16 + abase;
#pragma unroll
    for (int kt = 0; kt < 8; ++kt) {
      const int k0 = kt * 32 + koff;
      const float4 v0 = *(const float4*)(Wh + (size_t)grow * HDIM + k0);
      const float4 v1 = *(const float4*)(Wh + (size_t)grow * HDIM + k0 + 4);
      bfrag f;
      f[0] = (short)f2bf(v0.x); f[1] = (short)f2bf(v0.y);
      f[2] = (short)f2bf(v0.z); f[3] = (short)f2bf(v0.w);
      f[4] = (short)f2bf(v1.x); f[5] = (short)f2bf(v1.y);
      f[6] = (short)f2bf(v1.z); f[7] = (short)f2bf(v1.w);
      wr[ct][kt] = f;
    }
  }

  float hreg[8];
#pragma unroll
  for (int i = 0; i < 8; ++i) hreg[i] = 0.f;

  // Gate-phase thread mapping: colpair cp = tid&127 (cols 2cp, 2cp+1),
  // row group rgrp = tid>>7 (rows 4*rgrp .. 4*rgrp+3). 8 h-values per thread.
  const int cp   = tid & 127;
  const int rgrp = tid >> 7;
  const int col0 = cp * 2;

  __syncthreads();

  for (int t = 0; t < SEQ; ++t) {
    // ---- Phase A ----
    // Prefetch this step's gx early (consumed in phase B ~2000 cycles later).
    unsigned int pg[12];  // [gate*4 + r], two bf16 each
    {
      const unsigned short* gbase = gx + ((size_t)t * BATCH + s * 16) * G3;
#pragma unroll
      for (int g = 0; g < 3; ++g)
#pragma unroll
        for (int r = 0; r < 4; ++r)
          pg[g * 4 + r] = *(const unsigned int*)(gbase + (size_t)(rgrp * 4 + r) * G3 + g * 256 + col0);
    }

    // gh = h . Wh^T for this wave's 96 columns.
    f32x4 acc[6];
#pragma unroll
    for (int ct = 0; ct < 6; ++ct) acc[ct] = (f32x4){0.f, 0.f, 0.f, 0.f};
#pragma unroll
    for (int kt = 0; kt < 8; ++kt) {
      const bfrag a = *(const bfrag*)&hs[abase][kt * 32 + koff];
#pragma unroll
      for (int ct = 0; ct < 5; ++ct)
        acc[ct] = __builtin_amdgcn_mfma_f32_16x16x32_bf16(a, wr[ct][kt], acc[ct], 0, 0, 0);
      const bfrag bl = *(const bfrag*)&WhL[w][abase][kt * 32 + koff];
      acc[5] = __builtin_amdgcn_mfma_f32_16x16x32_bf16(a, bl, acc[5], 0, 0, 0);
    }
#pragma unroll
    for (int ct = 0; ct < 6; ++ct)
#pragma unroll
      for (int i = 0; i < 4; ++i)
        ghs[(lane >> 4) * 4 + i][w * 96 + ct * 16 + abase] = acc[ct][i];
    __syncthreads();

    // ---- Phase B: gates ----
    const float2 br = *(const float2*)&bhs[col0];
    const float2 bz = *(const float2*)&bhs[256 + col0];
    const float2 bn = *(const float2*)&bhs[512 + col0];
#pragma unroll
    for (int r = 0; r < 4; ++r) {
      const int row = rgrp * 4 + r;
      const float2 gr = *(const float2*)&ghs[row][col0];
      const float2 gz = *(const float2*)&ghs[row][256 + col0];
      const float2 gn = *(const float2*)&ghs[row][512 + col0];
      const unsigned int ur = pg[r], uz = pg[4 + r], un = pg[8 + r];
      float hnew[2];
#pragma unroll
      for (int c = 0; c < 2; ++c) {
        const float xr = bf2f(c ? (unsigned short)(ur >> 16) : (unsigned short)(ur & 0xffff));
        const float xz = bf2f(c ? (unsigned short)(uz >> 16) : (unsigned short)(uz & 0xffff));
        const float xn = bf2f(c ? (unsigned short)(un >> 16) : (unsigned short)(un & 0xffff));
        const float hrv = (c ? gr.y : gr.x) + (c ? br.y : br.x);
        const float hzv = (c ? gz.y : gz.x) + (c ? bz.y : bz.x);
        const float hnv = (c ? gn.y : gn.x) + (c ? bn.y : bn.x);
        const float rg = fast_sigmoid(xr + hrv);
        const float zg = fast_sigmoid(xz + hzv);
        const float ng = fast_tanh(xn + rg * hnv);
        const float hold = hreg[r * 2 + c];
        const float hv = ng + zg * (hold - ng);
        hreg[r * 2 + c] = hv;
        hnew[c] = hv;
      }
      const unsigned int packed = (unsigned int)f2bf(hnew[0]) | ((unsigned int)f2bf(hnew[1]) << 16);
      *(unsigned int*)&hs[row][col0] = packed;
      if (t == SEQ - 1) {
        float* hp = hf + (size_t)(s * 16 + row) * HDIM + col0;
        hp[0] = hnew[0];
        hp[1] = hnew[1];
      }
    }
    __syncthreads();
  }
}

// ---------------------------------------------------------------------------
// Phase 3: out[b][o] = h_T[b][:] . Wfc[o][:] + bfc[o]   (tiny, f32)
// ---------------------------------------------------------------------------
__global__ __launch_bounds__(256) void gru_fc(const float* __restrict__ hf,
                                              const float* __restrict__ Wfc,
                                              const float* __restrict__ bfc,
                                              float* __restrict__ out) {
  const int tid = threadIdx.x;
  const int b = tid >> 1;
  const int o = tid & 1;
  float sum = bfc[o];
  for (int k = 0; k < HDIM; ++k)
    sum += hf[b * HDIM + k] * Wfc[o * HDIM + k];
  out[b * 2 + o] = sum;
}

// ---------------------------------------------------------------------------
extern "C" void kernel_launch(void* const* d_in, const int* in_sizes, int n_in,
                              void* d_out, int out_size, void* d_ws, size_t ws_size,
                              hipStream_t stream) {
  (void)in_sizes; (void)n_in; (void)out_size; (void)ws_size;
  const float* x   = (const float*)d_in[0];
  const float* Wx  = (const float*)d_in[1];
  const float* bx  = (const float*)d_in[2];
  const float* Wh  = (const float*)d_in[3];
  const float* bh  = (const float*)d_in[4];
  const float* Wfc = (const float*)d_in[5];
  const float* bfc = (const float*)d_in[6];
  float* out = (float*)d_out;

  char* ws = (char*)d_ws;
  const size_t GXB = (size_t)SEQ * BATCH * G3 * sizeof(unsigned short); // 402,653,184 B
  unsigned short* gx = (unsigned short*)ws;
  float*          hf = (float*)(ws + GXB);   // 128*256*4 = 131,072 B

  gx_gemm<<<SEQ, 512, 0, stream>>>(x, Wx, bx, gx);
  gru_scan<<<8, 512, 0, stream>>>(gx, Wh, bh, hf);
  gru_fc<<<1, 256, 0, stream>>>(hf, Wfc, bfc, out);
}